// Round 4
// baseline (175.851 us; speedup 1.0000x reference)
//
#include <hip/hip_runtime.h>
#include <stdint.h>

// Problem constants (from reference)
#define NB   4      // batch
#define CC   256    // channels (K)
#define WR   60     // cells per row/col
#define MM   3600   // HR*WR (M and N of the GEMM)
#define HH   480
#define WW   480
#define GS   8
#define MT   29     // ceil(3600/128) tiles per side
#define NBLK (MT * MT * NB)      // gemm grid size = 3364
#define PREPB 57                 // ceil(NB*MM / 256) blocks carrying prep work

typedef float f32x4  __attribute__((ext_vector_type(4)));
typedef float f32x16 __attribute__((ext_vector_type(16)));
typedef int   i32x8  __attribute__((ext_vector_type(8)));

// ---------------------------------------------------------------------------
// Kernel 1: pack desc[b][c][m] (f32) into MFMA-fragment fp8-e4m3 tiles for
// the MX-scaled v_mfma_f32_32x32x64_f8f6f4 (unity scales -> plain fp8 GEMM
// at 2x the non-scaled fp8 rate).
// Fragment layout (A operand, 32x32x64): lane l holds row (l&31),
//   k = kt*64 + (l>>5)*32 + byte  (32 contiguous bytes per lane).
// Packed tile per (b,mtile): 16 slots x 2048 B = 32 KB:
//   addr = base[b][mtile] + (kt*4 + t)*2048 + lane*32
// where t in [0,4) is the 32-row m-frag (m = mtile*128 + t*32 + (l&31)).
// Gather stays global-direct (no LDS): for a given c, the 32 low lanes read
// 32 consecutive floats (2 lines), the 32 high lanes read the same m-range
// at c+32 -> every 64-B line touched exactly once. Tail rows zero-filled.
// FUSED: blocks 0..56 do per-cell prep (warp grid + vis product); the
// per-block vm partial goes straight into Vacc via device atomicAdd
// (57 adds total — finalize kernel eliminated).
// ---------------------------------------------------------------------------
__global__ __launch_bounds__(256) void pack_prep(
    const float* __restrict__ d1, const float* __restrict__ d2,
    const float* __restrict__ homo, const float* __restrict__ vis,
    unsigned char* __restrict__ p1, unsigned char* __restrict__ p2,
    float2* __restrict__ wg, float* __restrict__ vmarr,
    float* __restrict__ acc_sv) {   // acc_sv[0]=Sacc, [1]=Vacc, [2]=counter
  __shared__ float vmred[4];
  int kt = blockIdx.x;      // 0..3  (K blocks of 64)
  int mtile = blockIdx.y;   // 0..28
  int z = blockIdx.z;       // 0..7  (desc,b)
  int bid = kt + 4 * (mtile + MT * z);
  int b = z & 3;
  const float* src = ((z >> 2) ? d2 : d1) + (size_t)b * CC * MM;
  unsigned char* dstbase = ((z >> 2) ? p2 : p1) + (size_t)(b * MT + mtile) * 32768;
  int tid = threadIdx.x;
  int t = tid >> 6, lane = tid & 63;
  int r = lane & 31, hi = lane >> 5;
  int m = mtile * 128 + t * 32 + r;
  int c0 = kt * 64 + hi * 32;

  unsigned int ww[8];
  if (m < MM) {
    const float* s0 = src + (size_t)c0 * MM + m;
#pragma unroll
    for (int d = 0; d < 8; ++d) {
      float f0 = s0[(size_t)(4 * d + 0) * MM];
      float f1 = s0[(size_t)(4 * d + 1) * MM];
      float f2 = s0[(size_t)(4 * d + 2) * MM];
      float f3 = s0[(size_t)(4 * d + 3) * MM];
      unsigned int wv = __builtin_amdgcn_cvt_pk_fp8_f32(f0, f1, 0, false);
      wv = __builtin_amdgcn_cvt_pk_fp8_f32(f2, f3, wv, true);
      ww[d] = wv;
    }
  } else {
#pragma unroll
    for (int d = 0; d < 8; ++d) ww[d] = 0;   // zero-pad tail -> dot = 0
  }
  uint4* dst = (uint4*)(dstbase + (size_t)(kt * 4 + t) * 2048 + lane * 32);
  dst[0] = make_uint4(ww[0], ww[1], ww[2], ww[3]);
  dst[1] = make_uint4(ww[4], ww[5], ww[6], ww[7]);

  // ---- fused prep (blocks 0..56 only; block-uniform branch) ----
  if (bid < PREPB) {
    int idx = bid * 256 + tid;
    float p = 0.f;
    if (idx < NB * MM) {
      int bb = idx / MM, cell = idx - bb * MM;
      int h1 = cell / WR, w1 = cell - h1 * WR;
      float gx = (float)(w1 * GS + GS / 2);
      float gy = (float)(h1 * GS + GS / 2);
      const float* Hm = homo + bb * 9;
      float X = Hm[0] * gx + Hm[1] * gy + Hm[2];
      float Y = Hm[3] * gx + Hm[4] * gy + Hm[5];
      float Z = Hm[6] * gx + Hm[7] * gy + Hm[8];
      wg[idx] = make_float2(X / Z, Y / Z);
      const float* v = vis + (size_t)bb * HH * WW + (size_t)(h1 * GS) * WW + w1 * GS;
      float prod = 1.f;
#pragma unroll
      for (int rr = 0; rr < GS; ++rr) {
        const float4* rp = (const float4*)(v + (size_t)rr * WW);
        float4 a = rp[0], c = rp[1];
        prod *= a.x * a.y * a.z * a.w;
        prod *= c.x * c.y * c.z * c.w;
      }
      vmarr[idx] = prod;
      p = prod;
    }
#pragma unroll
    for (int off = 32; off; off >>= 1) p += __shfl_down(p, off, 64);
    if ((tid & 63) == 0) vmred[tid >> 6] = p;
    __syncthreads();
    if (tid == 0)
      atomicAdd(&acc_sv[1], vmred[0] + vmred[1] + vmred[2] + vmred[3]);
  }
}

// ---------------------------------------------------------------------------
// Kernel 2: MX-scaled fp8 MFMA GEMM (32x32x64, unity E8M0 scales = 0x7F)
// + hinge loss + fused final reduction (device atomics + done-counter; the
// last block to finish divides and writes out).
// __launch_bounds__(256, 2): THE VERIFIED NO-SPILL CONFIG. acc 2x2xf32x16
// (64 regs, AGPR-allocated) + double-buffered operands (64) + addressing
// fits the 256-reg budget. (256,3) caps the budget at ~170 -> compiler
// spills MFMA operands to scratch: VGPR_Count=64, MfmaUtil 5%, gemm 99 us
// (Round-2 regression). (256,8) spills acc. NEVER tighten this bound.
// Bijective XCD swizzle (3364 % 8 == 4 -> m204 variant) keeps each XCD's
// packed panels hot in its private L2.
// ---------------------------------------------------------------------------
__global__ __launch_bounds__(256, 2) void hinge_gemm(
    const unsigned char* __restrict__ Ap, const unsigned char* __restrict__ Bp,
    const float2* __restrict__ wg, const float* __restrict__ vmarr,
    float* __restrict__ acc_sv, float* __restrict__ out) {
  __shared__ float partial[4];

  // --- bijective XCD-chunked swizzle over the flattened 3364-block grid ---
  int orig = blockIdx.x + MT * blockIdx.y + MT * MT * blockIdx.z;
  const int q = NBLK >> 3, rmod = NBLK & 7;   // 420, 4
  int xcd = orig & 7, loc = orig >> 3;
  int wgid = (xcd < rmod ? xcd * (q + 1) : rmod * (q + 1) + (xcd - rmod) * q) + loc;
  int b = wgid / (MT * MT);
  int rem = wgid - b * (MT * MT);
  int mtile = rem / MT;
  int ntile = rem - mtile * MT;

  int tid = threadIdx.x, lane = tid & 63, w = tid >> 6;
  int colL = lane & 31, hi = lane >> 5;
  int wave_m = w >> 1, wave_n = w & 1;   // 2x2 wave grid, 64x64 out per wave

  // per-lane fragment base: slot (kt*4 + wave_*2 + i) at base + slot*2048
  const char* Af = (const char*)Ap + (size_t)(b * MT + mtile) * 32768
                   + (size_t)(wave_m * 2) * 2048 + lane * 32;
  const char* Bf = (const char*)Bp + (size_t)(b * MT + ntile) * 32768
                   + (size_t)(wave_n * 2) * 2048 + lane * 32;

  f32x16 acc[2][2];
#pragma unroll
  for (int i = 0; i < 2; ++i)
#pragma unroll
    for (int j = 0; j < 2; ++j)
#pragma unroll
      for (int k = 0; k < 16; ++k) acc[i][j][k] = 0.f;

  i32x8 a0[2], b0[2], a1[2], b1[2];
#pragma unroll
  for (int t2 = 0; t2 < 2; ++t2) {
    a0[t2] = *(const i32x8*)(Af + t2 * 2048);
    b0[t2] = *(const i32x8*)(Bf + t2 * 2048);
  }

#pragma unroll
  for (int kt = 0; kt < 4; ++kt) {
    if (kt < 3) {   // register prefetch, distance 1 kt
      const char* an = Af + (kt + 1) * 8192;
      const char* bn = Bf + (kt + 1) * 8192;
#pragma unroll
      for (int t2 = 0; t2 < 2; ++t2) {
        a1[t2] = *(const i32x8*)(an + t2 * 2048);
        b1[t2] = *(const i32x8*)(bn + t2 * 2048);
      }
    }
#pragma unroll
    for (int mi = 0; mi < 2; ++mi)
#pragma unroll
      for (int ni = 0; ni < 2; ++ni)
        acc[mi][ni] = __builtin_amdgcn_mfma_scale_f32_32x32x64_f8f6f4(
            a0[mi], b0[ni], acc[mi][ni], 0, 0, /*fmt A,B = fp8 e4m3*/
            0, 127, 0, 127 /* E8M0 127 -> scale 1.0 */);
#pragma unroll
    for (int t2 = 0; t2 < 2; ++t2) { a0[t2] = a1[t2]; b0[t2] = b1[t2]; }
  }

  // Epilogue. C/D layout (32x32, dtype-independent, HW-verified):
  //   col = lane&31, row = (reg&3) + 8*(reg>>2) + 4*(lane>>5).
  // Tail m-rows are zero-padded in Ap -> dot=0; no m-guard needed.
  // Tail n guarded via vmv=0.
  float wx[2], wy[2], vv[2];
  const float2* wgb = wg + (size_t)b * MM;
  const float*  vmb = vmarr + (size_t)b * MM;
#pragma unroll
  for (int ni = 0; ni < 2; ++ni) {
    int gn = ntile * 128 + wave_n * 64 + ni * 32 + colL;
    bool nok = gn < MM;
    float2 wgv = nok ? wgb[gn] : make_float2(1e9f, 1e9f);
    wx[ni] = wgv.x; wy[ni] = wgv.y;
    vv[ni] = nok ? vmb[gn] : 0.f;
  }

  float sum = 0.f;
#pragma unroll
  for (int mi = 0; mi < 2; ++mi)
#pragma unroll
    for (int reg = 0; reg < 16; ++reg) {
      int gm = mtile * 128 + wave_m * 64 + mi * 32 + (reg & 3) + 8 * (reg >> 2) + 4 * hi;
      float gmf = (float)gm;
      float h1 = floorf(fmaf(gmf, (1.0f / 60.0f), (1.0f / 120.0f)));
      float w1 = fmaf(h1, -60.f, gmf);
      float gx = fmaf(w1, 8.f, 4.f);
      float gy = fmaf(h1, 8.f, 4.f);
#pragma unroll
      for (int ni = 0; ni < 2; ++ni) {
        float dot = acc[mi][ni][reg];
        float dx = gx - wx[ni];
        float dy = gy - wy[ni];
        float d2 = fmaf(dx, dx, dy * dy);
        float a = (d2 <= 56.25f) ? (1.0f - dot) : (dot - 0.2f);
        sum = fmaf(vv[ni], fmaxf(a, 0.f), sum);
      }
    }
#pragma unroll
  for (int off = 32; off; off >>= 1) sum += __shfl_down(sum, off, 64);
  if (lane == 0) partial[w] = sum;
  __syncthreads();
  if (tid == 0) {
    atomicAdd(&acc_sv[0], partial[0] + partial[1] + partial[2] + partial[3]);
    __threadfence();
    unsigned old = atomicAdd((unsigned*)&acc_sv[2], 1u);
    if (old == (unsigned)(NBLK - 1)) {
      // all S-adds (and pack's V-adds, stream-ordered earlier) are visible;
      // atomic read-modify-write returns the device-coherent value.
      float S = atomicAdd(&acc_sv[0], 0.f);
      float V = atomicAdd(&acc_sv[1], 0.f);
      out[0] = S / ((float)MM * V);
    }
  }
}

extern "C" void kernel_launch(void* const* d_in, const int* in_sizes, int n_in,
                              void* d_out, int out_size, void* d_ws, size_t ws_size,
                              hipStream_t stream) {
  const float* desc1 = (const float*)d_in[0];
  const float* desc2 = (const float*)d_in[1];
  const float* homo  = (const float*)d_in[2];
  const float* vis   = (const float*)d_in[3];
  float* out = (float*)d_out;

  char* ws = (char*)d_ws;
  // packed size per desc: 4 * 29 * 32768 B = 3,801,088 B
  unsigned char* Ap = (unsigned char*)ws;
  unsigned char* Bp = (unsigned char*)(ws + 3801088);
  float2* wg      = (float2*)(ws + 7602176);          // 115,200 B
  float*  vm      = (float*) (ws + 7717376);          //  57,600 B
  float*  acc_sv  = (float*) (ws + 7774976);          // S, V, counter (12 B)

  // zero the S/V accumulators and done-counter (graph-capturable stream op)
  hipMemsetAsync(acc_sv, 0, 12, stream);

  dim3 pgrid(4, MT, 2 * NB);   // kt(64-wide) x mtile x (desc,b); fused prep
  pack_prep<<<pgrid, 256, 0, stream>>>(desc1, desc2, homo, vis, Ap, Bp,
                                       wg, vm, acc_sv);

  dim3 ggrid(MT, MT, NB);
  hinge_gemm<<<ggrid, 256, 0, stream>>>(Ap, Bp, wg, vm, acc_sv, out);
}

// Round 5
// 113.984 us; speedup vs baseline: 1.5428x; 1.5428x over previous
//
#include <hip/hip_runtime.h>
#include <stdint.h>

// Problem constants (from reference)
#define NB   4      // batch
#define CC   256    // channels (K)
#define WR   60     // cells per row/col
#define MM   3600   // HR*WR (M and N of the GEMM)
#define HH   480
#define WW   480
#define GS   8
#define MT   29     // ceil(3600/128) tiles per side
#define NBLK (MT * MT * NB)      // gemm grid size = 3364
#define PREPB 57                 // ceil(NB*MM / 256) blocks carrying prep work

typedef float f32x4  __attribute__((ext_vector_type(4)));
typedef float f32x16 __attribute__((ext_vector_type(16)));
typedef int   i32x8  __attribute__((ext_vector_type(8)));

// ---------------------------------------------------------------------------
// Kernel 1: pack desc[b][c][m] (f32) into MFMA-fragment fp8-e4m3 tiles for
// the MX-scaled v_mfma_f32_32x32x64_f8f6f4 (unity scales -> plain fp8 GEMM
// at 2x the non-scaled fp8 rate).
// Fragment layout (A operand, 32x32x64): lane l holds row (l&31),
//   k = kt*64 + (l>>5)*32 + byte  (32 contiguous bytes per lane).
// Packed tile per (b,mtile): 16 slots x 2048 B = 32 KB:
//   addr = base[b][mtile] + (kt*4 + t)*2048 + lane*32
// where t in [0,4) is the 32-row m-frag (m = mtile*128 + t*32 + (l&31)).
// Gather stays global-direct (no LDS): for a given c, the 32 low lanes read
// 32 consecutive floats (2 lines), the 32 high lanes read the same m-range
// at c+32 -> every 64-B line touched exactly once. Tail rows zero-filled.
// FUSED: blocks 0..56 do per-cell prep. vm partial -> PRIVATE vm_part slot
// (NO device atomics: Round-2/4 lesson — same-address device-scope atomics
// from a full grid serialize cross-XCD at ~30ns each; 3364 of them = 100us.
// Private writes + a 3us reduce kernel are strictly cheaper.)
// ---------------------------------------------------------------------------
__global__ __launch_bounds__(256) void pack_prep(
    const float* __restrict__ d1, const float* __restrict__ d2,
    const float* __restrict__ homo, const float* __restrict__ vis,
    unsigned char* __restrict__ p1, unsigned char* __restrict__ p2,
    float2* __restrict__ wg, float* __restrict__ vmarr,
    float* __restrict__ vm_part) {
  __shared__ float vmred[4];
  int kt = blockIdx.x;      // 0..3  (K blocks of 64)
  int mtile = blockIdx.y;   // 0..28
  int z = blockIdx.z;       // 0..7  (desc,b)
  int bid = kt + 4 * (mtile + MT * z);
  int b = z & 3;
  const float* src = ((z >> 2) ? d2 : d1) + (size_t)b * CC * MM;
  unsigned char* dstbase = ((z >> 2) ? p2 : p1) + (size_t)(b * MT + mtile) * 32768;
  int tid = threadIdx.x;
  int t = tid >> 6, lane = tid & 63;
  int r = lane & 31, hi = lane >> 5;
  int m = mtile * 128 + t * 32 + r;
  int c0 = kt * 64 + hi * 32;

  unsigned int ww[8];
  if (m < MM) {
    const float* s0 = src + (size_t)c0 * MM + m;
#pragma unroll
    for (int d = 0; d < 8; ++d) {
      float f0 = s0[(size_t)(4 * d + 0) * MM];
      float f1 = s0[(size_t)(4 * d + 1) * MM];
      float f2 = s0[(size_t)(4 * d + 2) * MM];
      float f3 = s0[(size_t)(4 * d + 3) * MM];
      unsigned int wv = __builtin_amdgcn_cvt_pk_fp8_f32(f0, f1, 0, false);
      wv = __builtin_amdgcn_cvt_pk_fp8_f32(f2, f3, wv, true);
      ww[d] = wv;
    }
  } else {
#pragma unroll
    for (int d = 0; d < 8; ++d) ww[d] = 0;   // zero-pad tail -> dot = 0
  }
  uint4* dst = (uint4*)(dstbase + (size_t)(kt * 4 + t) * 2048 + lane * 32);
  dst[0] = make_uint4(ww[0], ww[1], ww[2], ww[3]);
  dst[1] = make_uint4(ww[4], ww[5], ww[6], ww[7]);

  // ---- fused prep (blocks 0..56 only; block-uniform branch) ----
  if (bid < PREPB) {
    int idx = bid * 256 + tid;
    float p = 0.f;
    if (idx < NB * MM) {
      int bb = idx / MM, cell = idx - bb * MM;
      int h1 = cell / WR, w1 = cell - h1 * WR;
      float gx = (float)(w1 * GS + GS / 2);
      float gy = (float)(h1 * GS + GS / 2);
      const float* Hm = homo + bb * 9;
      float X = Hm[0] * gx + Hm[1] * gy + Hm[2];
      float Y = Hm[3] * gx + Hm[4] * gy + Hm[5];
      float Z = Hm[6] * gx + Hm[7] * gy + Hm[8];
      wg[idx] = make_float2(X / Z, Y / Z);
      const float* v = vis + (size_t)bb * HH * WW + (size_t)(h1 * GS) * WW + w1 * GS;
      float prod = 1.f;
#pragma unroll
      for (int rr = 0; rr < GS; ++rr) {
        const float4* rp = (const float4*)(v + (size_t)rr * WW);
        float4 a = rp[0], c = rp[1];
        prod *= a.x * a.y * a.z * a.w;
        prod *= c.x * c.y * c.z * c.w;
      }
      vmarr[idx] = prod;
      p = prod;
    }
#pragma unroll
    for (int off = 32; off; off >>= 1) p += __shfl_down(p, off, 64);
    if ((tid & 63) == 0) vmred[tid >> 6] = p;
    __syncthreads();
    if (tid == 0)
      vm_part[bid] = vmred[0] + vmred[1] + vmred[2] + vmred[3];
  }
}

// ---------------------------------------------------------------------------
// Kernel 2: MX-scaled fp8 MFMA GEMM (32x32x64, unity E8M0 scales = 0x7F)
// + hinge loss. No LDS staging, no K-loop barriers, and — critically —
// NO ATOMICS: each block writes a private block_part slot. (Round-2/4
// lesson: a fused atomic finalize with a same-address done-counter
// serialized the whole grid: 3364 device-scope RMWs to one line = ~100us
// dispatch, MfmaUtil 5%, all pipes idle. Never route a grid through one
// atomic address.)
// __launch_bounds__(256, 2): verified no-spill config (Round-1, gemm <15us).
// Bijective XCD swizzle (3364 % 8 == 4 -> m204 variant) keeps each XCD's
// packed panels hot in its private L2.
// ---------------------------------------------------------------------------
__global__ __launch_bounds__(256, 2) void hinge_gemm(
    const unsigned char* __restrict__ Ap, const unsigned char* __restrict__ Bp,
    const float2* __restrict__ wg, const float* __restrict__ vmarr,
    float* __restrict__ block_part) {
  __shared__ float partial[4];

  // --- bijective XCD-chunked swizzle over the flattened 3364-block grid ---
  int orig = blockIdx.x + MT * blockIdx.y + MT * MT * blockIdx.z;
  const int q = NBLK >> 3, rmod = NBLK & 7;   // 420, 4
  int xcd = orig & 7, loc = orig >> 3;
  int wgid = (xcd < rmod ? xcd * (q + 1) : rmod * (q + 1) + (xcd - rmod) * q) + loc;
  int b = wgid / (MT * MT);
  int rem = wgid - b * (MT * MT);
  int mtile = rem / MT;
  int ntile = rem - mtile * MT;

  int tid = threadIdx.x, lane = tid & 63, w = tid >> 6;
  int colL = lane & 31, hi = lane >> 5;
  int wave_m = w >> 1, wave_n = w & 1;   // 2x2 wave grid, 64x64 out per wave

  // per-lane fragment base: slot (kt*4 + wave_*2 + i) at base + slot*2048
  const char* Af = (const char*)Ap + (size_t)(b * MT + mtile) * 32768
                   + (size_t)(wave_m * 2) * 2048 + lane * 32;
  const char* Bf = (const char*)Bp + (size_t)(b * MT + ntile) * 32768
                   + (size_t)(wave_n * 2) * 2048 + lane * 32;

  f32x16 acc[2][2];
#pragma unroll
  for (int i = 0; i < 2; ++i)
#pragma unroll
    for (int j = 0; j < 2; ++j)
#pragma unroll
      for (int k = 0; k < 16; ++k) acc[i][j][k] = 0.f;

  i32x8 a0[2], b0[2], a1[2], b1[2];
#pragma unroll
  for (int t2 = 0; t2 < 2; ++t2) {
    a0[t2] = *(const i32x8*)(Af + t2 * 2048);
    b0[t2] = *(const i32x8*)(Bf + t2 * 2048);
  }

#pragma unroll
  for (int kt = 0; kt < 4; ++kt) {
    if (kt < 3) {   // register prefetch, distance 1 kt
      const char* an = Af + (kt + 1) * 8192;
      const char* bn = Bf + (kt + 1) * 8192;
#pragma unroll
      for (int t2 = 0; t2 < 2; ++t2) {
        a1[t2] = *(const i32x8*)(an + t2 * 2048);
        b1[t2] = *(const i32x8*)(bn + t2 * 2048);
      }
    }
#pragma unroll
    for (int mi = 0; mi < 2; ++mi)
#pragma unroll
      for (int ni = 0; ni < 2; ++ni)
        acc[mi][ni] = __builtin_amdgcn_mfma_scale_f32_32x32x64_f8f6f4(
            a0[mi], b0[ni], acc[mi][ni], 0, 0, /*fmt A,B = fp8 e4m3*/
            0, 127, 0, 127 /* E8M0 127 -> scale 1.0 */);
#pragma unroll
    for (int t2 = 0; t2 < 2; ++t2) { a0[t2] = a1[t2]; b0[t2] = b1[t2]; }
  }

  // Epilogue. C/D layout (32x32, dtype-independent, HW-verified):
  //   col = lane&31, row = (reg&3) + 8*(reg>>2) + 4*(lane>>5).
  // Tail m-rows are zero-padded in Ap -> dot=0; no m-guard needed.
  // Tail n guarded via vmv=0.
  float gxv[32], gyv[32];
#pragma unroll
  for (int mi = 0; mi < 2; ++mi)
#pragma unroll
    for (int reg = 0; reg < 16; ++reg) {
      int gm = mtile * 128 + wave_m * 64 + mi * 32 + (reg & 3) + 8 * (reg >> 2) + 4 * hi;
      float gmf = (float)gm;
      float h1 = floorf(fmaf(gmf, (1.0f / 60.0f), (1.0f / 120.0f)));
      float w1 = fmaf(h1, -60.f, gmf);
      gxv[mi * 16 + reg] = fmaf(w1, 8.f, 4.f);
      gyv[mi * 16 + reg] = fmaf(h1, 8.f, 4.f);
    }

  float sum = 0.f;
  const float2* wgb = wg + (size_t)b * MM;
  const float*  vmb = vmarr + (size_t)b * MM;
#pragma unroll
  for (int ni = 0; ni < 2; ++ni) {
    int gn = ntile * 128 + wave_n * 64 + ni * 32 + colL;
    bool nok = gn < MM;
    float2 wgv = nok ? wgb[gn] : make_float2(1e9f, 1e9f);
    float  vmv = nok ? vmb[gn] : 0.f;
#pragma unroll
    for (int mi = 0; mi < 2; ++mi)
#pragma unroll
      for (int reg = 0; reg < 16; ++reg) {
        float dot = acc[mi][ni][reg];
        float dx = gxv[mi * 16 + reg] - wgv.x;
        float dy = gyv[mi * 16 + reg] - wgv.y;
        float d2 = fmaf(dx, dx, dy * dy);
        float a = (d2 <= 56.25f) ? (1.0f - dot) : (dot - 0.2f);
        sum = fmaf(vmv, fmaxf(a, 0.f), sum);
      }
  }
#pragma unroll
  for (int off = 32; off; off >>= 1) sum += __shfl_down(sum, off, 64);
  if (lane == 0) partial[w] = sum;
  __syncthreads();
  if (tid == 0) {
    int fbid = ntile + MT * (mtile + MT * b);
    block_part[fbid] = partial[0] + partial[1] + partial[2] + partial[3];
  }
}

// ---------------------------------------------------------------------------
// Kernel 3: reduce 3364 block partials + 57 vm partials; write output.
// ---------------------------------------------------------------------------
__global__ __launch_bounds__(256) void finalize_k(
    const float* __restrict__ block_part, const float* __restrict__ vm_part,
    float* __restrict__ out) {
  __shared__ float red[8];
  int tid = threadIdx.x;
  float s = 0.f, v = 0.f;
  for (int i = tid; i < NBLK; i += 256) s += block_part[i];
  if (tid < PREPB) v = vm_part[tid];
#pragma unroll
  for (int off = 32; off; off >>= 1) {
    s += __shfl_down(s, off, 64);
    v += __shfl_down(v, off, 64);
  }
  if ((tid & 63) == 0) { red[tid >> 6] = s; red[4 + (tid >> 6)] = v; }
  __syncthreads();
  if (tid == 0) {
    float S = red[0] + red[1] + red[2] + red[3];
    float V = red[4] + red[5] + red[6] + red[7];
    out[0] = S / ((float)MM * V);
  }
}

extern "C" void kernel_launch(void* const* d_in, const int* in_sizes, int n_in,
                              void* d_out, int out_size, void* d_ws, size_t ws_size,
                              hipStream_t stream) {
  const float* desc1 = (const float*)d_in[0];
  const float* desc2 = (const float*)d_in[1];
  const float* homo  = (const float*)d_in[2];
  const float* vis   = (const float*)d_in[3];
  float* out = (float*)d_out;

  char* ws = (char*)d_ws;
  // packed size per desc: 4 * 29 * 32768 B = 3,801,088 B
  unsigned char* Ap = (unsigned char*)ws;
  unsigned char* Bp = (unsigned char*)(ws + 3801088);
  float2* wg         = (float2*)(ws + 7602176);          // 115,200 B
  float*  vm         = (float*) (ws + 7717376);          //  57,600 B
  float*  vm_part    = (float*) (ws + 7774976);          // 57 * 4 B
  float*  block_part = (float*) (ws + 7775232);          // 3364 * 4 B

  dim3 pgrid(4, MT, 2 * NB);   // kt(64-wide) x mtile x (desc,b); fused prep
  pack_prep<<<pgrid, 256, 0, stream>>>(desc1, desc2, homo, vis, Ap, Bp,
                                       wg, vm, vm_part);

  dim3 ggrid(MT, MT, NB);
  hinge_gemm<<<ggrid, 256, 0, stream>>>(Ap, Bp, wg, vm, block_part);

  finalize_k<<<1, 256, 0, stream>>>(block_part, vm_part, out);
}